// Round 5
// baseline (178.283 us; speedup 1.0000x reference)
//
#include <hip/hip_runtime.h>

typedef unsigned int u32;
typedef unsigned short u16;
typedef __attribute__((ext_vector_type(4))) float f32x4;
typedef __attribute__((ext_vector_type(8))) __bf16 bf16x8;
typedef __attribute__((ext_vector_type(4))) u32 u32x4;

// fp32 -> bf16 round-to-nearest-even
__device__ __forceinline__ u32 f2bf(float f) {
    u32 u = __builtin_bit_cast(u32, f);
    return (u + 0x7fffu + ((u >> 16) & 1u)) >> 16;
}
// fp32 -> bf16 round-half-up (cheaper; only on hidden activations)
__device__ __forceinline__ u32 f2bf_fast(float f) {
    u32 u = __builtin_bit_cast(u32, f);
    return (u + 0x8000u) >> 16;
}
__device__ __forceinline__ u32 pk2(float lo, float hi) {
    return f2bf(lo) | (f2bf(hi) << 16);
}
// unpack bf16 pair from u32 (NOTE: do NOT use __bf16 vector arithmetic on
// gfx950 — R4 showed it miscompiles; unpack to f32 explicitly)
__device__ __forceinline__ float bflo(u32 a) { return __builtin_bit_cast(float, a << 16); }
__device__ __forceinline__ float bfhi(u32 a) { return __builtin_bit_cast(float, a & 0xffff0000u); }

// 16 rows x 136 bf16 (+8 pad: 2-way-max bank aliasing = free per m136)
union LdsTile {
    u16 h[16 * 136];
    u32x4 v[16 * 17];
};

// ---------------------------------------------------------------------------
// Precompute kernel. relu comes AFTER the edge sum, so layer 1 factors
// per-node:  hidden = relu(np[src] + ap[dst])
//   blocks [0, nbr_blocks):      np[s] = x_nbr[s]  . W1[0:128]        (bf16)
//   blocks [nbr_blocks, grid):   ap[a] = x_agent[a]. W1[128:256] + b1 (bf16)
//                                own   = x_agent . Wa + ba -> out[256..263]
//                                zero-fill out[128..255]
// ---------------------------------------------------------------------------
__global__ __launch_bounds__(256, 2)
void precompute_kernel(const float* __restrict__ x_nbr,
                       const float* __restrict__ x_agent,
                       const float* __restrict__ W1,
                       const float* __restrict__ b1,
                       const float* __restrict__ Wa,
                       const float* __restrict__ ba,
                       u16* __restrict__ np, u16* __restrict__ ap,
                       float* __restrict__ out,
                       int n_nodes, int n_agents, int nbr_blocks)
{
    __shared__ LdsTile Abuf[4];
    const int wid = threadIdx.x >> 6;
    const int l   = threadIdx.x & 63;
    const int n   = l & 15;
    const int q   = l >> 4;
    const bool is_nbr = (int)blockIdx.x < nbr_blocks;

    // W1 half fragments: rows [0,128) for nbr part, [128,256) for agent part
    const float* Wb = W1 + (is_nbr ? 0 : 128 * 128);
    u32x4 wf[8][4];
#pragma unroll
    for (int nt = 0; nt < 8; ++nt) {
        const int col = nt * 16 + n;
#pragma unroll
        for (int kk = 0; kk < 4; ++kk) {
            u32x4 w;
#pragma unroll
            for (int jp = 0; jp < 4; ++jp) {
                const int k = kk * 32 + q * 8 + jp * 2;
                w[jp] = pk2(Wb[(size_t)k * 128 + col], Wb[(size_t)(k + 1) * 128 + col]);
            }
            wf[nt][kk] = w;
        }
    }
    const f32x4 zero = {0.f, 0.f, 0.f, 0.f};

    if (is_nbr) {
        const int n_tiles = n_nodes >> 4;
        const int gw = blockIdx.x * 4 + wid;
        const int stride = nbr_blocks * 4;
        for (int t = gw; t < n_tiles; t += stride) {
            const int a0 = t * 16;
#pragma unroll
            for (int it = 0; it < 4; ++it) {
                const int m = it * 4 + q;
                const float* bp = x_nbr + (size_t)(a0 + m) * 128 + n * 8;
                const float4 v0 = *(const float4*)bp;
                const float4 v1 = *(const float4*)(bp + 4);
                u32x4 pkv;
                pkv[0] = pk2(v0.x, v0.y); pkv[1] = pk2(v0.z, v0.w);
                pkv[2] = pk2(v1.x, v1.y); pkv[3] = pk2(v1.z, v1.w);
                Abuf[wid].v[m * 17 + n] = pkv;
            }
            f32x4 acc[8];
#pragma unroll
            for (int nt = 0; nt < 8; ++nt) acc[nt] = zero;
#pragma unroll
            for (int kk = 0; kk < 4; ++kk) {
                const u32x4 a = Abuf[wid].v[n * 17 + kk * 4 + q];
#pragma unroll
                for (int nt = 0; nt < 8; ++nt)
                    acc[nt] = __builtin_amdgcn_mfma_f32_16x16x32_bf16(
                        __builtin_bit_cast(bf16x8, a),
                        __builtin_bit_cast(bf16x8, wf[nt][kk]), acc[nt], 0, 0, 0);
            }
#pragma unroll
            for (int nt = 0; nt < 8; ++nt)
#pragma unroll
                for (int r = 0; r < 4; ++r)
                    np[(size_t)(a0 + q * 4 + r) * 128 + nt * 16 + n] =
                        (u16)f2bf(acc[nt][r]);
        }
    } else {
        u32x4 waf[4];
#pragma unroll
        for (int kk = 0; kk < 4; ++kk) {
            u32x4 w;
#pragma unroll
            for (int jp = 0; jp < 4; ++jp) {
                const int k = kk * 32 + q * 8 + jp * 2;
                const float f0 = (n < 8) ? Wa[(size_t)k * 8 + n] : 0.f;
                const float f1 = (n < 8) ? Wa[(size_t)(k + 1) * 8 + n] : 0.f;
                w[jp] = pk2(f0, f1);
            }
            waf[kk] = w;
        }
        float b1v[8];
#pragma unroll
        for (int nt = 0; nt < 8; ++nt) b1v[nt] = b1[nt * 16 + n];
        const float bav = (n < 8) ? ba[n] : 0.f;

        const int n_tiles = n_agents >> 4;
        const int agent_blocks = gridDim.x - nbr_blocks;
        const int gw = (blockIdx.x - nbr_blocks) * 4 + wid;
        const int stride = agent_blocks * 4;
        for (int t = gw; t < n_tiles; t += stride) {
            const int a0 = t * 16;
#pragma unroll
            for (int it = 0; it < 4; ++it) {
                const int m = it * 4 + q;
                const float* bp = x_agent + (size_t)(a0 + m) * 128 + n * 8;
                const float4 v0 = *(const float4*)bp;
                const float4 v1 = *(const float4*)(bp + 4);
                u32x4 pkv;
                pkv[0] = pk2(v0.x, v0.y); pkv[1] = pk2(v0.z, v0.w);
                pkv[2] = pk2(v1.x, v1.y); pkv[3] = pk2(v1.z, v1.w);
                Abuf[wid].v[m * 17 + n] = pkv;
            }
            f32x4 acc[8];
#pragma unroll
            for (int nt = 0; nt < 8; ++nt) acc[nt] = zero;
            f32x4 acca = zero;
#pragma unroll
            for (int kk = 0; kk < 4; ++kk) {
                const u32x4 a = Abuf[wid].v[n * 17 + kk * 4 + q];
#pragma unroll
                for (int nt = 0; nt < 8; ++nt)
                    acc[nt] = __builtin_amdgcn_mfma_f32_16x16x32_bf16(
                        __builtin_bit_cast(bf16x8, a),
                        __builtin_bit_cast(bf16x8, wf[nt][kk]), acc[nt], 0, 0, 0);
                acca = __builtin_amdgcn_mfma_f32_16x16x32_bf16(
                    __builtin_bit_cast(bf16x8, a),
                    __builtin_bit_cast(bf16x8, waf[kk]), acca, 0, 0, 0);
            }
#pragma unroll
            for (int nt = 0; nt < 8; ++nt)
#pragma unroll
                for (int r = 0; r < 4; ++r)
                    ap[(size_t)(a0 + q * 4 + r) * 128 + nt * 16 + n] =
                        (u16)f2bf(acc[nt][r] + b1v[nt]);
            const float4 z = {0.f, 0.f, 0.f, 0.f};
#pragma unroll
            for (int it = 0; it < 4; ++it) {
                const int m = it * 4 + q;
                float4* zp = (float4*)(out + (size_t)(a0 + m) * 264 + 128 + n * 8);
                zp[0] = z; zp[1] = z;
            }
#pragma unroll
            for (int r = 0; r < 4; ++r) {
                const int m = q * 4 + r;
                if (n < 8) out[(size_t)(a0 + m) * 264 + 256 + n] = acca[r] + bav;
            }
        }
    }
}

// ---------------------------------------------------------------------------
// Edge kernel: per 16-edge tile (one dst agent): gather np[src] rows directly
// in MFMA A-fragment layout, f32 add + relu with ap[dst], repack bf16,
// 4 MFMAs vs W2, store. No LDS, no barriers. Ping-pong prefetch + grid 2048
// (8 blocks/CU = 32 waves/CU at 56 VGPR) to hide random-gather latency.
// ---------------------------------------------------------------------------
#define EDGE_STEP(cnp, cap, csrc, cslot, cdst, nnp, nap, nsrc, nslot, ndst)      \
  {                                                                              \
    const int t2 = (t1 + stride < n_tiles) ? t1 + stride : t1;                   \
    _Pragma("unroll") for (int kk = 0; kk < 4; ++kk) {                           \
        const int s = __shfl(nsrc, n);                                           \
        nnp[kk] = *(const u32x4*)(np + (size_t)s * 128 + kk * 32 + q * 8);       \
    }                                                                            \
    _Pragma("unroll") for (int kk = 0; kk < 4; ++kk)                             \
        nap[kk] = *(const u32x4*)(ap + (size_t)ndst * 128 + kk * 32 + q * 8);    \
    const int sdst = cdst;                                                       \
    const int sslot = cslot;                                                     \
    const bool done = (t1 == t);                                                 \
    if (!done) {                                                                 \
        if (l < 16) { csrc = edge_src[t2 * 16 + l]; cslot = edge_slot[t2 * 16 + l]; } \
        cdst = edge_dst[t2 * 16];                                                \
    }                                                                            \
    f32x4 acc2 = {0.f, 0.f, 0.f, 0.f};                                           \
    _Pragma("unroll") for (int kk = 0; kk < 4; ++kk) {                           \
        u32x4 hf;                                                                \
        _Pragma("unroll") for (int j = 0; j < 4; ++j) {                          \
            const u32 av = cnp[kk][j], bv = cap[kk][j];                          \
            const float lo = fmaxf(bflo(av) + bflo(bv), 0.f);                    \
            const float hi = fmaxf(bfhi(av) + bfhi(bv), 0.f);                    \
            hf[j] = f2bf_fast(lo) | (f2bf_fast(hi) << 16);                       \
        }                                                                        \
        acc2 = __builtin_amdgcn_mfma_f32_16x16x32_bf16(                          \
            __builtin_bit_cast(bf16x8, hf),                                      \
            __builtin_bit_cast(bf16x8, w2f[kk]), acc2, 0, 0, 0);                 \
    }                                                                            \
    float* orow = out + (size_t)sdst * 264;                                      \
    _Pragma("unroll") for (int r = 0; r < 4; ++r) {                              \
        const int sl = __shfl(sslot, q * 4 + r);                                 \
        if (n < 8) orow[sl * 8 + n] = acc2[r] + b2v;                             \
    }                                                                            \
    if (done) break;                                                             \
    t = t1; t1 = t2;                                                             \
  }

__global__ __launch_bounds__(256, 4)
void edge_kernel(const u16* __restrict__ np, const u16* __restrict__ ap,
                 const float* __restrict__ W2, const float* __restrict__ b2,
                 const int* __restrict__ edge_src,
                 const int* __restrict__ edge_dst,
                 const int* __restrict__ edge_slot,
                 float* __restrict__ out, int n_tiles)
{
    const int wid = threadIdx.x >> 6;
    const int l   = threadIdx.x & 63;
    const int n   = l & 15;
    const int q   = l >> 4;

    // W2 B-fragments (N padded 8->16 with zeros): 16 VGPRs
    u32x4 w2f[4];
#pragma unroll
    for (int kk = 0; kk < 4; ++kk) {
        u32x4 w;
#pragma unroll
        for (int jp = 0; jp < 4; ++jp) {
            const int k = kk * 32 + q * 8 + jp * 2;
            const float f0 = (n < 8) ? W2[(size_t)k * 8 + n] : 0.f;
            const float f1 = (n < 8) ? W2[(size_t)(k + 1) * 8 + n] : 0.f;
            w[jp] = pk2(f0, f1);
        }
        w2f[kk] = w;
    }
    const float b2v = (n < 8) ? b2[n] : 0.f;

    const int stride = gridDim.x * 4;
    int t = blockIdx.x * 4 + wid;
    if (t >= n_tiles) return;

    // prologue: idx for t and t1, frags for t
    int src0 = 0, slot0 = 0;
    if (l < 16) { src0 = edge_src[t * 16 + l]; slot0 = edge_slot[t * 16 + l]; }
    int dst0 = edge_dst[t * 16];
    int t1 = (t + stride < n_tiles) ? t + stride : t;
    int src1 = 0, slot1 = 0;
    if (l < 16) { src1 = edge_src[t1 * 16 + l]; slot1 = edge_slot[t1 * 16 + l]; }
    int dst1 = edge_dst[t1 * 16];

    u32x4 np0[4], ap0[4], np1[4], ap1[4];
#pragma unroll
    for (int kk = 0; kk < 4; ++kk) {
        const int s = __shfl(src0, n);
        np0[kk] = *(const u32x4*)(np + (size_t)s * 128 + kk * 32 + q * 8);
    }
#pragma unroll
    for (int kk = 0; kk < 4; ++kk)
        ap0[kk] = *(const u32x4*)(ap + (size_t)dst0 * 128 + kk * 32 + q * 8);

    while (true) {
        EDGE_STEP(np0, ap0, src0, slot0, dst0, np1, ap1, src1, slot1, dst1)
        EDGE_STEP(np1, ap1, src1, slot1, dst1, np0, ap0, src0, slot0, dst0)
    }
}

extern "C" void kernel_launch(void* const* d_in, const int* in_sizes, int n_in,
                              void* d_out, int out_size, void* d_ws, size_t ws_size,
                              hipStream_t stream)
{
    const float* x_nbr   = (const float*)d_in[0];
    const float* x_agent = (const float*)d_in[1];
    const float* W1      = (const float*)d_in[2];
    const float* b1      = (const float*)d_in[3];
    const float* W2      = (const float*)d_in[4];
    const float* b2      = (const float*)d_in[5];
    const float* Wa      = (const float*)d_in[6];
    const float* ba      = (const float*)d_in[7];
    const int* edge_src  = (const int*)d_in[8];
    const int* edge_dst  = (const int*)d_in[9];
    const int* edge_slot = (const int*)d_in[10];

    const int E        = in_sizes[8];
    const int n_nodes  = in_sizes[0] / 128;
    const int n_agents = in_sizes[1] / 128;
    const int n_tiles  = E / 16;

    // ws: np (n_nodes*128 bf16 = 12.8 MB) | ap (n_agents*128 bf16 = 12.8 MB)
    u16* np = (u16*)d_ws;
    u16* ap = (u16*)d_ws + (size_t)n_nodes * 128;

    const int nbr_blocks = 512, agent_blocks = 512;
    precompute_kernel<<<dim3(nbr_blocks + agent_blocks), dim3(256), 0, stream>>>(
        x_nbr, x_agent, W1, b1, Wa, ba, np, ap, (float*)d_out,
        n_nodes, n_agents, nbr_blocks);
    // 2048 blocks = 8 blocks/CU = 32 waves/CU at 56 VGPR
    edge_kernel<<<dim3(2048), dim3(256), 0, stream>>>(
        np, ap, W2, b2, edge_src, edge_dst, edge_slot, (float*)d_out, n_tiles);
}